// Round 3
// baseline (119.053 us; speedup 1.0000x reference)
//
#include <hip/hip_runtime.h>
#include <math.h>

// GMM score, rescaled: out_j = (E_w[td] - x_j) / sigma2_j
// w_i = exp(-0.5 (td_i - x_j)^2 / sigma2_j), sigma2_j = (exp(2 t_j ln25)-1)/(2 ln25)
//
// Timing model: dur = ~41us harness ws-poison (fixed, 256MiB fill @83% HBM)
//   + gmm_partial + gmm_final + gaps.
// R2 finding: JPT=1 (2048 blk) and JPT=2 (1024 blk, 2x ILP) both measure
// 40.8us -> hard per-element throughput ceiling. Back-solve: v_exp_f32 costs
// ~20 cyc/wave64 instr (trans pipe ~1/8 rate). Kernel is TRANS-PIPE-BOUND.
// R3 (this round): replace v_exp_f32 with packed-math exp2:
//   k=rndne(arg); f=arg-k; p=poly4(f) [4x v_pk_fma]; w=ldexp(p, int(k)).
// ldexp is HW-clamped (k<<0 -> 0), so huge-negative args flush to 0 weight.
// Per 2-elem bundle per j: 9 pk @2 + 6 scalar-VALU @2 = 30 cyc vs 48 now.
// Prediction: partial 40.8 -> 25-28us, VALUBusy 63% -> >=85%, total ~77-80us.
// Poly rel err ~4e-5 (relative in w) -> evals err ~2e-4, absmax unchanged.

typedef float v2f __attribute__((ext_vector_type(2)));

#define BLK   256
#define JPT   2      // outputs per thread
#define CH    512    // train elements per slice (2 KB LDS); S = N/CH = 32

#if __has_builtin(__builtin_amdgcn_ldexpf)
#define LDEXP(x, k) __builtin_amdgcn_ldexpf((x), (k))
#else
#define LDEXP(x, k) ldexpf((x), (k))
#endif

#if __has_builtin(__builtin_elementwise_roundeven)
#define RNDNE2(v) __builtin_elementwise_roundeven(v)
#else
__device__ __forceinline__ v2f rndne2_(v2f v) { v2f r; r.x = rintf(v.x); r.y = rintf(v.y); return r; }
#define RNDNE2(v) rndne2_(v)
#endif

__device__ __forceinline__ float sigma2_of(float tj) {
  const float TWO_LOG_S = 6.4377516497364011f;   // 2*ln(25)
  return (__expf(TWO_LOG_S * tj) - 1.0f) / TWO_LOG_S;
}

template <bool ATOMIC>
__launch_bounds__(BLK, 4)
__global__ void gmm_partial(const float* __restrict__ x,
                            const float* __restrict__ t,
                            const float* __restrict__ td,
                            float* __restrict__ ws,
                            int N, int B) {
  __shared__ float lds[CH];
  const int tid  = threadIdx.x;
  const int j0   = blockIdx.x * (BLK * JPT) + tid;   // first output index
  const int j1   = j0 + BLK;                          // second output index
  const int s    = blockIdx.y;                        // N-slice
  const int S    = gridDim.y;
  const int base = s * CH;

  for (int i = tid; i < CH; i += BLK) {
    int gi = base + i;
    // pad: large-but-finite -> arg ~ -7e32 -> k saturates to INT_MIN ->
    // ldexp flushes to 0 (weightless). (1e30 would make d^2=inf -> NaN in
    // the poly path; 1e15 keeps d^2 finite.)
    lds[i] = (gi < N) ? td[gi] : 1e15f;
  }

  const float HALF_LOG2E = 0.72134752044448170f;  // 0.5 * log2(e)
  float r0 = 0.0f, y0 = 0.0f, r1 = 0.0f, y1 = 0.0f;
  if (j0 < B) {
    float s2 = sigma2_of(t[j0]);
    r0 = __fsqrt_rn(HALF_LOG2E / s2);   // d = (td - x)*r ; arg = -d^2 (base-2)
    y0 = x[j0] * r0;
  }
  if (j1 < B) {
    float s2 = sigma2_of(t[j1]);
    r1 = __fsqrt_rn(HALF_LOG2E / s2);
    y1 = x[j1] * r1;
  }
  __syncthreads();

  const v2f rv0  = {r0, r0};
  const v2f nyv0 = {-y0, -y0};
  const v2f rv1  = {r1, r1};
  const v2f nyv1 = {-y1, -y1};

  // exp2 poly coefficients (Taylor/minimax, rel err ~4e-5 on [-0.5,0.5])
  const v2f C1 = {0.693147182f, 0.693147182f};
  const v2f C2 = {0.240226507f, 0.240226507f};
  const v2f C3 = {0.055504109f, 0.055504109f};
  const v2f C4 = {0.009618129f, 0.009618129f};
  const v2f ONE = {1.0f, 1.0f};

  // per-j accumulators: 2 num + 2 den (v2f) each
  v2f n00 = {0.f, 0.f}, n01 = {0.f, 0.f}, d00 = {0.f, 0.f}, d01 = {0.f, 0.f};
  v2f n10 = {0.f, 0.f}, n11 = {0.f, 0.f}, d10 = {0.f, 0.f}, d11 = {0.f, 0.f};

  const float4* l4 = (const float4*)lds;   // ds_read_b128 broadcast, conflict-free
  const int iters = CH >> 3;               // 8 td elements per iteration

  // w = exp2(arg), arg = -(d^2) <= 0:
  //   k = rndne(arg); f = arg - k in [-0.5,0.5]; p = 2^f (poly4);
  //   w = ldexp(p, (int)k)   (v_ldexp_f32: k <= -150 -> 0, HW-clamped)
#define EXP2V(arg, w)                                                   \
  {                                                                     \
    v2f kf_ = RNDNE2(arg);                                              \
    v2f f_  = (arg) - kf_;                                              \
    v2f p_  = __builtin_elementwise_fma(f_, C4, C3);                    \
    p_      = __builtin_elementwise_fma(f_, p_, C2);                    \
    p_      = __builtin_elementwise_fma(f_, p_, C1);                    \
    p_      = __builtin_elementwise_fma(f_, p_, ONE);                   \
    (w).x   = LDEXP(p_.x, (int)kf_.x);                                  \
    (w).y   = LDEXP(p_.y, (int)kf_.y);                                  \
  }

#define GROUP(v, naccA, daccA, naccB, daccB)                            \
  {                                                                     \
    v2f dA = __builtin_elementwise_fma(v, rv0, nyv0);                   \
    v2f dB = __builtin_elementwise_fma(v, rv1, nyv1);                   \
    v2f aA = -(dA * dA);   /* pk_mul with neg modifier */               \
    v2f aB = -(dB * dB);                                                \
    v2f pA, pB;                                                         \
    EXP2V(aA, pA)                                                       \
    EXP2V(aB, pB)                                                       \
    daccA += pA;                                                        \
    daccB += pB;                                                        \
    naccA = __builtin_elementwise_fma(pA, v, naccA);                    \
    naccB = __builtin_elementwise_fma(pB, v, naccB);                    \
  }

  #pragma unroll 2
  for (int i = 0; i < iters; ++i) {
    float4 v0 = l4[2 * i];
    float4 v1 = l4[2 * i + 1];
    v2f va = {v0.x, v0.y}, vb = {v0.z, v0.w};
    v2f vc = {v1.x, v1.y}, vd = {v1.z, v1.w};
    GROUP(va, n00, d00, n10, d10)
    GROUP(vb, n01, d01, n11, d11)
    GROUP(vc, n00, d00, n10, d10)
    GROUP(vd, n01, d01, n11, d11)
  }
#undef GROUP
#undef EXP2V

  v2f numv0 = n00 + n01, denv0 = d00 + d01;
  v2f numv1 = n10 + n11, denv1 = d10 + d11;
  float num0 = numv0.x + numv0.y, den0 = denv0.x + denv0.y;
  float num1 = numv1.x + numv1.y, den1 = denv1.x + denv1.y;

  if (j0 < B) {
    if (ATOMIC) {
      atomicAdd(&ws[j0], num0);
      atomicAdd(&ws[B + j0], den0);
    } else {
      ws[(size_t)s * B + j0]       = num0;   // num partials: [S][B]
      ws[(size_t)(S + s) * B + j0] = den0;   // den partials: [S][B]
    }
  }
  if (j1 < B) {
    if (ATOMIC) {
      atomicAdd(&ws[j1], num1);
      atomicAdd(&ws[B + j1], den1);
    } else {
      ws[(size_t)s * B + j1]       = num1;
      ws[(size_t)(S + s) * B + j1] = den1;
    }
  }
}

// Parallel final reduction: block = 32 j's x 8 slice-groups; each thread sums
// slices s = g, g+8, g+16, ... (coalesced across the 32 j-lanes), then LDS
// combine over the 8 groups and epilogue. Grid = ceil(B/32) blocks.
#define FJ 32   // j's per final block
#define FG 8    // slice-groups per final block
__launch_bounds__(FJ * FG)
__global__ void gmm_final(const float* __restrict__ x,
                          const float* __restrict__ t,
                          const float* __restrict__ ws,
                          float* __restrict__ out, int B, int S) {
  __shared__ float nbuf[FG * FJ];
  __shared__ float dbuf[FG * FJ];
  const int tid = threadIdx.x;
  const int jl  = tid & (FJ - 1);     // j lane
  const int g   = tid >> 5;           // slice group
  const int j   = blockIdx.x * FJ + jl;

  float np = 0.f, dp = 0.f;
  if (j < B) {
    for (int s = g; s < S; s += FG) {
      np += ws[(size_t)s * B + j];
      dp += ws[(size_t)(S + s) * B + j];
    }
  }
  nbuf[tid] = np;
  dbuf[tid] = dp;
  __syncthreads();

  if (g == 0 && j < B) {
    float num = 0.f, den = 0.f;
    #pragma unroll
    for (int gg = 0; gg < FG; ++gg) {
      num += nbuf[gg * FJ + jl];
      den += dbuf[gg * FJ + jl];
    }
    float sigma2 = sigma2_of(t[j]);
    float evals = (den == 0.0f) ? 0.0f : (num / den);   // reference's den==0 guard
    out[j] = (evals - x[j]) / sigma2;
  }
}

__global__ void gmm_final_serial(const float* __restrict__ x,
                                 const float* __restrict__ t,
                                 const float* __restrict__ ws,
                                 float* __restrict__ out, int B, int S) {
  int j = blockIdx.x * blockDim.x + threadIdx.x;
  if (j >= B) return;
  float num = 0.f, den = 0.f;
  for (int s = 0; s < S; ++s) {
    num += ws[(size_t)s * B + j];
    den += ws[(size_t)(S + s) * B + j];
  }
  float sigma2 = sigma2_of(t[j]);
  float evals = (den == 0.0f) ? 0.0f : (num / den);
  out[j] = (evals - x[j]) / sigma2;
}

__global__ void zero_kernel(float* __restrict__ p, int n) {
  int i = blockIdx.x * blockDim.x + threadIdx.x;
  if (i < n) p[i] = 0.0f;
}

extern "C" void kernel_launch(void* const* d_in, const int* in_sizes, int n_in,
                              void* d_out, int out_size, void* d_ws, size_t ws_size,
                              hipStream_t stream) {
  const float* x  = (const float*)d_in[0];
  const float* t  = (const float*)d_in[1];
  const float* td = (const float*)d_in[2];
  float* out = (float*)d_out;
  float* ws  = (float*)d_ws;

  const int B = in_sizes[0];
  const int N = in_sizes[2];

  const int S = (N + CH - 1) / CH;                  // 32 for N=16384
  size_t need = (size_t)2 * S * B * sizeof(float);  // 4 MB

  const int JBLK = BLK * JPT;                       // outputs per block = 512

  if (ws_size >= need) {
    dim3 grid((B + JBLK - 1) / JBLK, S);            // (32, 32) = 1024 blocks
    gmm_partial<false><<<grid, BLK, 0, stream>>>(x, t, td, ws, N, B);
    gmm_final<<<(B + FJ - 1) / FJ, FJ * FG, 0, stream>>>(x, t, ws, out, B, S);
  } else {
    // Fallback: zero + atomic accumulate + serial final (3 dispatches)
    int nzero = 2 * B;
    zero_kernel<<<(nzero + 255) / 256, 256, 0, stream>>>(ws, nzero);
    dim3 grid((B + JBLK - 1) / JBLK, S);
    gmm_partial<true><<<grid, BLK, 0, stream>>>(x, t, td, ws, N, B);
    gmm_final_serial<<<(B + 255) / 256, 256, 0, stream>>>(x, t, ws, out, B, 1);
  }
}